// Round 1
// baseline (4756.767 us; speedup 1.0000x reference)
//
#include <hip/hip_runtime.h>

#define DEV __device__ __forceinline__

typedef __attribute__((ext_vector_type(8))) short bf16x8;
typedef __attribute__((ext_vector_type(4))) float f32x4;
typedef __attribute__((ext_vector_type(2))) _Float16 h2_t;

// ---------- constants ----------
static const int V = 50000, E = 128, H = 256, B = 32, S = 256, T = 32, FF = 4096;
static const int NCT = 391;           // ceil(50000/128)
// workspace offsets (in floats)
static const size_t OFF_XKF  = 0;                     // S*B*4H = 8388608
static const size_t OFF_XKB  = 8388608;               // 8388608
static const size_t OFF_XKD  = 16777216;              // T*B*4H = 1048576
static const size_t OFF_HSF  = 17825792;              // S*B*H = 2097152
static const size_t OFF_HSB  = 19922944;              // 2097152
static const size_t OFF_HENC = 22020096;              // B*S*E = 1048576
static const size_t OFF_ERPF = 23068672;              // 131072 (uint)
static const size_t OFF_ERPB = 23199744;
static const size_t OFF_DRP  = 23330816;
static const size_t OFF_COMB = 23461888;              // 1024*768 ushort = 393216 floats
static const size_t OFF_FB16 = 23855104;              // 1024*4096 ushort = 2097152 floats
static const size_t OFF_PMAX = 25952256;              // 1024*391
static const size_t OFF_PSUM = 26352640;
static const size_t OFF_TLOG = 26753024;
static const size_t OFF_NLL  = 26754048;

// ---------- helpers ----------
DEV float sigf(float x) { return 1.0f / (1.0f + __expf(-x)); }
DEV float tanh_(float x) {
    x = fminf(fmaxf(x, -20.0f), 20.0f);
    float e = __expf(2.0f * x);
    return (e - 1.0f) / (e + 1.0f);
}
DEV unsigned short f2bf(float f) {
    unsigned int u = __builtin_bit_cast(unsigned int, f);
    u += 0x7FFFu + ((u >> 16) & 1u);
    return (unsigned short)(u >> 16);
}
DEV float bf2f(unsigned short s) {
    unsigned int u = ((unsigned int)s) << 16;
    return __builtin_bit_cast(float, u);
}
DEV float dot2u(unsigned int a, unsigned int b, float c) {
#if __has_builtin(__builtin_amdgcn_fdot2)
    return __builtin_amdgcn_fdot2(__builtin_bit_cast(h2_t, a), __builtin_bit_cast(h2_t, b), c, false);
#else
    h2_t x = __builtin_bit_cast(h2_t, a), y = __builtin_bit_cast(h2_t, b);
    return c + (float)x[0] * (float)y[0] + (float)x[1] * (float)y[1];
#endif
}

// ---------- K0: pack recurrent weights (H x 4H fp32) -> [k2][c] half2 dwords ----------
__global__ void pack_half_k(const float* __restrict__ erf, const float* __restrict__ erb,
                            const float* __restrict__ dr,
                            unsigned int* __restrict__ pf, unsigned int* __restrict__ pb,
                            unsigned int* __restrict__ pd) {
    int id = blockIdx.x * 256 + threadIdx.x;          // 3*131072 total
    int which = id >> 17;
    int rem = id & 131071;
    int k2 = rem >> 10, cc = rem & 1023;
    const float* s = (which == 0) ? erf : (which == 1) ? erb : dr;
    unsigned int* o = (which == 0) ? pf : (which == 1) ? pb : pd;
    float v0 = s[(2 * k2) * 1024 + cc];
    float v1 = s[(2 * k2 + 1) * 1024 + cc];
    h2_t h; h[0] = (_Float16)v0; h[1] = (_Float16)v1;
    o[rem] = __builtin_bit_cast(unsigned int, h);
}

// ---------- K1: gathered x@W + b  (M x 128)@(128 x 1024) ----------
__global__ __launch_bounds__(256) void xgate_kernel(const float* __restrict__ emb,
                                                    const int* __restrict__ tok_src, int dec_mode,
                                                    const float* __restrict__ wt,
                                                    const float* __restrict__ bias,
                                                    float* __restrict__ out) {
    __shared__ float Al[64][128];
    __shared__ int tk[64];
    int r0 = blockIdx.x * 64, c0b = blockIdx.y * 128;
    int tid = threadIdx.x;
    if (tid < 64) {
        int r = r0 + tid; int hi = r >> 5, b = r & 31; int token;
        if (dec_mode) token = (hi == 0) ? 2 : tok_src[b * 32 + hi];
        else          token = tok_src[b * 256 + hi];
        tk[tid] = token;
    }
    __syncthreads();
    {
        int ri = tid >> 2, cc = (tid & 3) * 32;
        const float4* src = (const float4*)&emb[(size_t)tk[ri] * 128 + cc];
        float4* dst = (float4*)&Al[ri][cc];
#pragma unroll
        for (int i = 0; i < 8; ++i) dst[i] = src[i];
    }
    __syncthreads();
    int rg = tid >> 5;
    int c = c0b + (tid & 31) * 4;
    float4 acc[8];
#pragma unroll
    for (int r = 0; r < 8; ++r) acc[r] = make_float4(0.f, 0.f, 0.f, 0.f);
    for (int k = 0; k < 128; k += 4) {
        float4 w0 = *(const float4*)&wt[(k + 0) * 1024 + c];
        float4 w1 = *(const float4*)&wt[(k + 1) * 1024 + c];
        float4 w2 = *(const float4*)&wt[(k + 2) * 1024 + c];
        float4 w3 = *(const float4*)&wt[(k + 3) * 1024 + c];
#pragma unroll
        for (int r = 0; r < 8; ++r) {
            float4 a = *(const float4*)&Al[rg * 8 + r][k];
            acc[r].x += a.x * w0.x + a.y * w1.x + a.z * w2.x + a.w * w3.x;
            acc[r].y += a.x * w0.y + a.y * w1.y + a.z * w2.y + a.w * w3.y;
            acc[r].z += a.x * w0.z + a.y * w1.z + a.z * w2.z + a.w * w3.z;
            acc[r].w += a.x * w0.w + a.y * w1.w + a.z * w2.w + a.w * w3.w;
        }
    }
    float4 b4 = *(const float4*)&bias[c];
#pragma unroll
    for (int r = 0; r < 8; ++r) {
        int row = r0 + rg * 8 + r;
        float4 v = make_float4(acc[r].x + b4.x, acc[r].y + b4.y, acc[r].z + b4.z, acc[r].w + b4.w);
        *(float4*)&out[(size_t)row * 1024 + c] = v;
    }
}

// ---------- K2: encoder LSTM recurrence, one block per (dir,batch row) ----------
__global__ __launch_bounds__(256) void enc_lstm(const float* __restrict__ xkf, const float* __restrict__ xkb,
                                                const unsigned int* __restrict__ erpf,
                                                const unsigned int* __restrict__ erpb,
                                                float* __restrict__ hsf, float* __restrict__ hsb) {
    int dir = blockIdx.x >> 5, row = blockIdx.x & 31;
    const float* xk = dir ? xkb : xkf;
    const unsigned int* erp = dir ? erpb : erpf;
    float* hs = dir ? hsb : hsf;
    int tid = threadIdx.x;
    __shared__ unsigned int h2[128];
    __shared__ float zg[1024];
    if (tid < 128) h2[tid] = 0u;
    float c_reg = 0.0f;
    __syncthreads();
    int c0 = tid * 4;
    const uint4* wp = (const uint4*)&erp[c0];
    for (int si = 0; si < 256; ++si) {
        int s = dir ? (255 - si) : si;
        float4 a = *(const float4*)&xk[(size_t)(s * 32 + row) * 1024 + c0];
        float acc0 = a.x, acc1 = a.y, acc2 = a.z, acc3 = a.w;
#pragma unroll 8
        for (int k2 = 0; k2 < 128; ++k2) {
            unsigned int hh = h2[k2];
            uint4 wq = wp[k2 * 256];
            acc0 = dot2u(hh, wq.x, acc0);
            acc1 = dot2u(hh, wq.y, acc1);
            acc2 = dot2u(hh, wq.z, acc2);
            acc3 = dot2u(hh, wq.w, acc3);
        }
        zg[c0] = acc0; zg[c0 + 1] = acc1; zg[c0 + 2] = acc2; zg[c0 + 3] = acc3;
        __syncthreads();
        {
            float ii = zg[tid], ff = zg[tid + 256], gg = zg[tid + 512], oo = zg[tid + 768];
            c_reg = sigf(ff) * c_reg + sigf(ii) * tanh_(gg);
            float h = sigf(oo) * tanh_(c_reg);
            ((_Float16*)h2)[tid] = (_Float16)h;
            hs[(size_t)(s * 32 + row) * 256 + tid] = h;
        }
        __syncthreads();
    }
}

// ---------- K3: henc_proj = enc @ henc_w + henc_b ----------
__global__ __launch_bounds__(256) void henc_kernel(const float* __restrict__ hsf, const float* __restrict__ hsb,
                                                   const float* __restrict__ hw, const float* __restrict__ hb,
                                                   float* __restrict__ henc) {
    __shared__ float Al[32][256];
    int r0 = blockIdx.x * 32;
    int tid = threadIdx.x;
    int rg = tid >> 5;
    int c = (tid & 31) * 4;
    float4 acc[4];
#pragma unroll
    for (int r = 0; r < 4; ++r) acc[r] = make_float4(0.f, 0.f, 0.f, 0.f);
    for (int kc = 0; kc < 2; ++kc) {
        const float* src_arr = kc ? hsb : hsf;
        {
            int ri = tid >> 3, cc = (tid & 7) * 32;
            int r = r0 + ri; int b = r >> 8, s = r & 255;
            const float4* sp = (const float4*)&src_arr[(size_t)(s * 32 + b) * 256 + cc];
            float4* dp = (float4*)&Al[ri][cc];
#pragma unroll
            for (int i = 0; i < 8; ++i) dp[i] = sp[i];
        }
        __syncthreads();
        for (int k = 0; k < 256; k += 4) {
            int kg = kc * 256 + k;
            float4 w0 = *(const float4*)&hw[(kg + 0) * 128 + c];
            float4 w1 = *(const float4*)&hw[(kg + 1) * 128 + c];
            float4 w2 = *(const float4*)&hw[(kg + 2) * 128 + c];
            float4 w3 = *(const float4*)&hw[(kg + 3) * 128 + c];
#pragma unroll
            for (int r = 0; r < 4; ++r) {
                float4 a = *(const float4*)&Al[rg * 4 + r][k];
                acc[r].x += a.x * w0.x + a.y * w1.x + a.z * w2.x + a.w * w3.x;
                acc[r].y += a.x * w0.y + a.y * w1.y + a.z * w2.y + a.w * w3.y;
                acc[r].z += a.x * w0.z + a.y * w1.z + a.z * w2.z + a.w * w3.z;
                acc[r].w += a.x * w0.w + a.y * w1.w + a.z * w2.w + a.w * w3.w;
            }
        }
        __syncthreads();
    }
    float4 b4 = *(const float4*)&hb[c];
#pragma unroll
    for (int r = 0; r < 4; ++r) {
        int row = r0 + rg * 4 + r;
        float4 v = make_float4(acc[r].x + b4.x, acc[r].y + b4.y, acc[r].z + b4.z, acc[r].w + b4.w);
        *(float4*)&henc[(size_t)row * 128 + c] = v;
    }
}

// ---------- K4: decoder LSTM + attention, one block per batch row ----------
__global__ __launch_bounds__(256) void decoder_kernel(const float* __restrict__ xkd,
                                                      const unsigned int* __restrict__ drp,
                                                      const float* __restrict__ sdw, const float* __restrict__ sdb,
                                                      const float* __restrict__ vatt,
                                                      const float* __restrict__ henc,
                                                      const float* __restrict__ hsf, const float* __restrict__ hsb,
                                                      unsigned short* __restrict__ comb16) {
    int row = blockIdx.x;
    int tid = threadIdx.x;
    __shared__ unsigned int h2[128];
    __shared__ float c_lds[256];
    __shared__ float zg[1024];
    __shared__ float catt[128];
    __shared__ float attn[256];
    __shared__ float red[256];
    __shared__ float vat[128];
    if (tid < 128) { h2[tid] = 0u; vat[tid] = vatt[tid]; }
    c_lds[tid] = 0.0f;
    __syncthreads();
    int c0 = tid * 4;
    const uint4* wp = (const uint4*)&drp[c0];
    for (int t = 0; t < 31; ++t) {
        // phase a: zg = x@dk + h@dr + db  (x-part precomputed)
        float4 a = *(const float4*)&xkd[(size_t)(t * 32 + row) * 1024 + c0];
        float acc0 = a.x, acc1 = a.y, acc2 = a.z, acc3 = a.w;
#pragma unroll 8
        for (int k2 = 0; k2 < 128; ++k2) {
            unsigned int hh = h2[k2];
            uint4 wq = wp[k2 * 256];
            acc0 = dot2u(hh, wq.x, acc0);
            acc1 = dot2u(hh, wq.y, acc1);
            acc2 = dot2u(hh, wq.z, acc2);
            acc3 = dot2u(hh, wq.w, acc3);
        }
        zg[c0] = acc0; zg[c0 + 1] = acc1; zg[c0 + 2] = acc2; zg[c0 + 3] = acc3;
        __syncthreads();
        // phase b: gates
        {
            float ii = zg[tid], ff = zg[tid + 256], gg = zg[tid + 512], oo = zg[tid + 768];
            float c = sigf(ff) * c_lds[tid] + sigf(ii) * tanh_(gg);
            float h = sigf(oo) * tanh_(c);
            c_lds[tid] = c;
            ((_Float16*)h2)[tid] = (_Float16)h;
        }
        __syncthreads();
        // phase c: catt = c @ sdec_w + sdec_b
        if (tid < 128) {
            float aa = sdb[tid];
            for (int k = 0; k < 256; ++k) aa += c_lds[k] * sdw[k * 128 + tid];
            catt[tid] = aa;
        }
        __syncthreads();
        // phase d: attention logits
        {
            const float4* hp = (const float4*)&henc[(size_t)(row * 256 + tid) * 128];
            float aa = 0.0f;
#pragma unroll 4
            for (int e4 = 0; e4 < 32; ++e4) {
                float4 h4 = hp[e4];
                int e = 4 * e4;
                aa += tanh_(h4.x + catt[e + 0]) * vat[e + 0];
                aa += tanh_(h4.y + catt[e + 1]) * vat[e + 1];
                aa += tanh_(h4.z + catt[e + 2]) * vat[e + 2];
                aa += tanh_(h4.w + catt[e + 3]) * vat[e + 3];
            }
            attn[tid] = aa;
        }
        __syncthreads();
        // phase e: softmax over S
        red[tid] = attn[tid];
        __syncthreads();
        for (int off = 128; off; off >>= 1) {
            if (tid < off) red[tid] = fmaxf(red[tid], red[tid + off]);
            __syncthreads();
        }
        float mx = red[0];
        __syncthreads();
        float ex = __expf(attn[tid] - mx);
        red[tid] = ex;
        __syncthreads();
        for (int off = 128; off; off >>= 1) {
            if (tid < off) red[tid] += red[tid + off];
            __syncthreads();
        }
        float inv = 1.0f / red[0];
        __syncthreads();
        attn[tid] = ex * inv;
        __syncthreads();
        // phase f: context + write combined (bf16)
        {
            float cx0 = 0.0f, cx1 = 0.0f;
#pragma unroll 4
            for (int s = 0; s < 256; ++s) {
                float aw = attn[s];
                cx0 += aw * hsf[(size_t)(s * 32 + row) * 256 + tid];
                cx1 += aw * hsb[(size_t)(s * 32 + row) * 256 + tid];
            }
            size_t base = (size_t)(t * 32 + row) * 768;
            comb16[base + tid] = f2bf(cx0);
            comb16[base + 256 + tid] = f2bf(cx1);
            comb16[base + 512 + tid] = f2bf(c_lds[tid]);
        }
        __syncthreads();
    }
    // zero pad step t=31 (rows 992..1023)
    {
        size_t base = (size_t)(31 * 32 + row) * 768;
        for (int j = tid; j < 768; j += 256) comb16[base + j] = 0;
    }
}

// ---------- K5: big bf16 MFMA GEMM (M=1024), mode0: store bf16 C, mode1: lse partials ----------
template <int MODE>
__global__ __launch_bounds__(256) void gemm_big(const unsigned short* __restrict__ A, int lda, int K,
                                                const float* __restrict__ Bm, int Nstride,
                                                const float* __restrict__ bias,
                                                unsigned short* __restrict__ outC,
                                                float* __restrict__ Pmax, float* __restrict__ Psum, int nct) {
    __shared__ unsigned int Al[256 * 20];
    __shared__ unsigned int Bl[128 * 20];
    int rt = blockIdx.x, ct = blockIdx.y;
    int tid = threadIdx.x;
    int lane = tid & 63, w = tid >> 6;
    f32x4 acc[4][8];
#pragma unroll
    for (int i = 0; i < 4; ++i)
#pragma unroll
        for (int j = 0; j < 8; ++j) acc[i][j] = (f32x4){0.f, 0.f, 0.f, 0.f};

    int arow = rt * 256 + tid;
    const unsigned short* aptr = A + (size_t)arow * lda;
    int bn = tid & 127, bkh = tid >> 7;
    int coln = ct * 128 + bn;
    bool colok = (coln < Nstride);
    int iters = K / 32;
    for (int it = 0; it < iters; ++it) {
        int k0 = it * 32;
        // stage A (256x32 bf16 copy)
        {
            const uint4* as = (const uint4*)(aptr + k0);
            uint4* ad = (uint4*)&Al[tid * 20];
            ad[0] = as[0]; ad[1] = as[1]; ad[2] = as[2]; ad[3] = as[3];
        }
        // stage B (32x128 fp32 -> bf16, transposed [n][k])
        {
            const float* bp = Bm + (size_t)(k0 + bkh * 16) * Nstride + coln;
            unsigned int dw[8];
#pragma unroll
            for (int i = 0; i < 8; ++i) {
                float f0 = colok ? bp[(size_t)(2 * i) * Nstride] : 0.0f;
                float f1 = colok ? bp[(size_t)(2 * i + 1) * Nstride] : 0.0f;
                dw[i] = (unsigned int)f2bf(f0) | ((unsigned int)f2bf(f1) << 16);
            }
            uint4* bd = (uint4*)&Bl[bn * 20 + bkh * 8];
            bd[0] = make_uint4(dw[0], dw[1], dw[2], dw[3]);
            bd[1] = make_uint4(dw[4], dw[5], dw[6], dw[7]);
        }
        __syncthreads();
        bf16x8 af[4];
#pragma unroll
        for (int i = 0; i < 4; ++i) {
            int r = w * 64 + i * 16 + (lane & 15);
            af[i] = *(const bf16x8*)&Al[r * 20 + (lane >> 4) * 4];
        }
#pragma unroll
        for (int j = 0; j < 8; ++j) {
            int n = j * 16 + (lane & 15);
            bf16x8 bfr = *(const bf16x8*)&Bl[n * 20 + (lane >> 4) * 4];
#pragma unroll
            for (int i = 0; i < 4; ++i)
                acc[i][j] = __builtin_amdgcn_mfma_f32_16x16x32_bf16(af[i], bfr, acc[i][j], 0, 0, 0);
        }
        __syncthreads();
    }
    // epilogue
    float bv[8]; bool vok[8];
#pragma unroll
    for (int j = 0; j < 8; ++j) {
        int col = ct * 128 + j * 16 + (lane & 15);
        vok[j] = (col < Nstride);
        bv[j] = vok[j] ? bias[col] : 0.0f;
    }
    if (MODE == 0) {
#pragma unroll
        for (int i = 0; i < 4; ++i)
#pragma unroll
            for (int reg = 0; reg < 4; ++reg) {
                int row = rt * 256 + w * 64 + i * 16 + (lane >> 4) * 4 + reg;
#pragma unroll
                for (int j = 0; j < 8; ++j) {
                    int col = ct * 128 + j * 16 + (lane & 15);
                    outC[(size_t)row * 4096 + col] = f2bf(acc[i][j][reg] + bv[j]);
                }
            }
    } else {
#pragma unroll
        for (int i = 0; i < 4; ++i)
#pragma unroll
            for (int reg = 0; reg < 4; ++reg) {
                int row = rt * 256 + w * 64 + i * 16 + (lane >> 4) * 4 + reg;
                float v[8];
                float m = -1e30f;
#pragma unroll
                for (int j = 0; j < 8; ++j) {
                    v[j] = vok[j] ? (acc[i][j][reg] + bv[j]) : -1e30f;
                    m = fmaxf(m, v[j]);
                }
                m = fmaxf(m, __shfl_xor(m, 1));
                m = fmaxf(m, __shfl_xor(m, 2));
                m = fmaxf(m, __shfl_xor(m, 4));
                m = fmaxf(m, __shfl_xor(m, 8));
                float s = 0.0f;
#pragma unroll
                for (int j = 0; j < 8; ++j) s += __expf(v[j] - m);
                s += __shfl_xor(s, 1);
                s += __shfl_xor(s, 2);
                s += __shfl_xor(s, 4);
                s += __shfl_xor(s, 8);
                if ((lane & 15) == 0) {
                    Pmax[(size_t)row * nct + ct] = m;
                    Psum[(size_t)row * nct + ct] = s;
                }
            }
    }
}

// ---------- K5c: target logits (gathered column dot) ----------
__global__ __launch_bounds__(256) void tgt_dot(const unsigned short* __restrict__ Fb,
                                               const float* __restrict__ lvw, const float* __restrict__ lvb,
                                               const int* __restrict__ targ, float* __restrict__ tlog) {
    int row = blockIdx.x;
    int t = row >> 5, b = row & 31;
    __shared__ float red[256];
    float acc = 0.0f;
    int n = 0;
    if (t < 31) {
        n = targ[b * 32 + t + 1];
        for (int k = threadIdx.x; k < 4096; k += 256)
            acc += bf2f(Fb[(size_t)row * 4096 + k]) * lvw[(size_t)k * 50000 + n];
    }
    red[threadIdx.x] = acc;
    __syncthreads();
    for (int off = 128; off; off >>= 1) {
        if (threadIdx.x < off) red[threadIdx.x] += red[threadIdx.x + off];
        __syncthreads();
    }
    if (threadIdx.x == 0) tlog[row] = (t < 31) ? (red[0] + lvb[n]) : 0.0f;
}

// ---------- K5d: per-row logsumexp + nll ----------
__global__ __launch_bounds__(256) void lse_nll(const float* __restrict__ Pmax, const float* __restrict__ Psum,
                                               const float* __restrict__ tlog, const int* __restrict__ targ,
                                               float* __restrict__ nll) {
    int row = blockIdx.x;
    int t = row >> 5, b = row & 31;
    int tid = threadIdx.x;
    __shared__ float rm[256];
    __shared__ float rs[256];
    float m = -1e30f;
    for (int i = tid; i < NCT; i += 256) m = fmaxf(m, Pmax[(size_t)row * NCT + i]);
    rm[tid] = m;
    __syncthreads();
    for (int off = 128; off; off >>= 1) {
        if (tid < off) rm[tid] = fmaxf(rm[tid], rm[tid + off]);
        __syncthreads();
    }
    m = rm[0];
    float s = 0.0f;
    for (int i = tid; i < NCT; i += 256)
        s += Psum[(size_t)row * NCT + i] * __expf(Pmax[(size_t)row * NCT + i] - m);
    rs[tid] = s;
    __syncthreads();
    for (int off = 128; off; off >>= 1) {
        if (tid < off) rs[tid] += rs[tid + off];
        __syncthreads();
    }
    if (tid == 0) {
        float lse = m + logf(rs[0]);
        float out = 0.0f;
        if (t < 31) {
            int tg = targ[b * 32 + t + 1];
            if (tg != 0) out = lse - tlog[row];
        }
        nll[row] = out;
    }
}

// ---------- K6: final reduce ----------
__global__ __launch_bounds__(256) void finloss(const float* __restrict__ nll, float* __restrict__ out) {
    __shared__ float red[256];
    int tid = threadIdx.x;
    float a = 0.0f;
    for (int i = tid; i < 1024; i += 256) a += nll[i];
    red[tid] = a;
    __syncthreads();
    for (int off = 128; off; off >>= 1) {
        if (tid < off) red[tid] += red[tid + off];
        __syncthreads();
    }
    if (tid == 0) out[0] = red[0] * (1.0f / 1024.0f);
}

extern "C" void kernel_launch(void* const* d_in, const int* in_sizes, int n_in,
                              void* d_out, int out_size, void* d_ws, size_t ws_size,
                              hipStream_t stream) {
    const int* inp = (const int*)d_in[0];
    const int* targ = (const int*)d_in[1];
    const float* emb = (const float*)d_in[2];
    const float* ekf = (const float*)d_in[3];
    const float* erf = (const float*)d_in[4];
    const float* ebf = (const float*)d_in[5];
    const float* ekb = (const float*)d_in[6];
    const float* erb = (const float*)d_in[7];
    const float* ebb = (const float*)d_in[8];
    const float* dk  = (const float*)d_in[9];
    const float* dr  = (const float*)d_in[10];
    const float* db  = (const float*)d_in[11];
    const float* hw  = (const float*)d_in[12];
    const float* hb  = (const float*)d_in[13];
    const float* sdw = (const float*)d_in[14];
    const float* sdb = (const float*)d_in[15];
    const float* vat = (const float*)d_in[16];
    const float* lfw = (const float*)d_in[17];
    const float* lfb = (const float*)d_in[18];
    const float* lvw = (const float*)d_in[19];
    const float* lvb = (const float*)d_in[20];

    float* ws = (float*)d_ws;
    float* xkf = ws + OFF_XKF;
    float* xkb = ws + OFF_XKB;
    float* xkd = ws + OFF_XKD;
    float* hsf = ws + OFF_HSF;
    float* hsb = ws + OFF_HSB;
    float* henc = ws + OFF_HENC;
    unsigned int* erpf = (unsigned int*)(ws + OFF_ERPF);
    unsigned int* erpb = (unsigned int*)(ws + OFF_ERPB);
    unsigned int* drp  = (unsigned int*)(ws + OFF_DRP);
    unsigned short* comb16 = (unsigned short*)(ws + OFF_COMB);
    unsigned short* fb16   = (unsigned short*)(ws + OFF_FB16);
    float* pmax = ws + OFF_PMAX;
    float* psum = ws + OFF_PSUM;
    float* tlog = ws + OFF_TLOG;
    float* nllb = ws + OFF_NLL;

    hipLaunchKernelGGL(pack_half_k, dim3(1536), dim3(256), 0, stream, erf, erb, dr, erpf, erpb, drp);
    hipLaunchKernelGGL(xgate_kernel, dim3(128, 8), dim3(256), 0, stream, emb, inp, 0, ekf, ebf, xkf);
    hipLaunchKernelGGL(xgate_kernel, dim3(128, 8), dim3(256), 0, stream, emb, inp, 0, ekb, ebb, xkb);
    hipLaunchKernelGGL(xgate_kernel, dim3(16, 8), dim3(256), 0, stream, emb, targ, 1, dk, db, xkd);
    hipLaunchKernelGGL(enc_lstm, dim3(64), dim3(256), 0, stream, xkf, xkb, erpf, erpb, hsf, hsb);
    hipLaunchKernelGGL(henc_kernel, dim3(256), dim3(256), 0, stream, hsf, hsb, hw, hb, henc);
    hipLaunchKernelGGL(decoder_kernel, dim3(32), dim3(256), 0, stream, xkd, drp, sdw, sdb, vat, henc, hsf, hsb, comb16);
    hipLaunchKernelGGL((gemm_big<0>), dim3(4, 32), dim3(256), 0, stream,
                       comb16, 768, 768, lfw, 4096, lfb, fb16, (float*)nullptr, (float*)nullptr, 0);
    hipLaunchKernelGGL((gemm_big<1>), dim3(4, 391), dim3(256), 0, stream,
                       fb16, 4096, 4096, lvw, 50000, lvb, (unsigned short*)nullptr, pmax, psum, NCT);
    hipLaunchKernelGGL(tgt_dot, dim3(1024), dim3(256), 0, stream, fb16, lvw, lvb, targ, tlog);
    hipLaunchKernelGGL(lse_nll, dim3(1024), dim3(256), 0, stream, pmax, psum, tlog, targ, nllb);
    hipLaunchKernelGGL(finloss, dim3(1), dim3(256), 0, stream, nllb, (float*)d_out);
}